// Round 6
// baseline (1422.072 us; speedup 1.0000x reference)
//
#include <hip/hip_runtime.h>
#include <hip/hip_bf16.h>

// Problem constants: N=200000, C=128, K=32, B=16, 20 Sinkhorn iters.
#define C_DIM 128
#define K_DIM 32
#define N_ITERS 20
#define NSHARD 16
#define WPAD 136   // bf16 row pad: 136*2B = 272B = 68 words -> bank step 4/row (2-way = free)

typedef __attribute__((ext_vector_type(8))) short short8;      // 8 bf16 (4 VGPR) MFMA A/B frag
typedef __attribute__((ext_vector_type(4))) float f32x4;       // MFMA C/D frag
typedef __attribute__((ext_vector_type(4))) unsigned short us4;

__device__ __forceinline__ unsigned short f2bf(float f) {
    __hip_bfloat16 h = __float2bfloat16(f);   // round-to-nearest
    return *reinterpret_cast<unsigned short*>(&h);
}

// ---------------------------------------------------------------------------
// init: zero out / shards / barrier counters; transpose+convert W1,W2 to bf16
// ---------------------------------------------------------------------------
__global__ void init_kernel(float* __restrict__ out, int n_out,
                            float* __restrict__ zreg, int n_z,
                            const float* __restrict__ W1, const float* __restrict__ W2,
                            unsigned short* __restrict__ W1t,
                            unsigned short* __restrict__ W2t) {
    int i = blockIdx.x * blockDim.x + threadIdx.x;
    int stride = gridDim.x * blockDim.x;
    for (int j = i; j < n_out; j += stride) out[j] = 0.f;
    for (int j = i; j < n_z; j += stride) zreg[j] = 0.f;
    for (int j = i; j < C_DIM * C_DIM; j += stride) {   // W1t[n][k] = W1[k][n]
        int n = j >> 7, k = j & 127;
        W1t[j] = f2bf(W1[k * C_DIM + n]);
    }
    for (int j = i; j < C_DIM * K_DIM; j += stride) {   // W2t[n][k] = W2[k][n]
        int n = j >> 7, k = j & 127;
        W2t[j] = f2bf(W2[k * K_DIM + n]);
    }
}

// ---------------------------------------------------------------------------
// MFMA MLP: L = (relu(x@W1 + b1) @ W2 + b2) * sc, bf16 inputs / fp32 accum.
// 256 thr (4 waves), 64-row tiles (wave = 16 rows). mfma_f32_16x16x32_bf16:
// A-frag lane l: A[l&15][(l>>4)*8 + j]; B-frag lane l: B[(l>>4)*8+j][l&15];
// D lane l reg r: D[(l>>4)*4 + r][l&15]  (m89-verified C/D layout).
// W staged once per block from pre-converted W1t/W2t; h re-fragmented via
// wave-private LDS region.
// ---------------------------------------------------------------------------
__global__ __launch_bounds__(256, 4) void mlp_kernel(
    const float* __restrict__ x, const unsigned short* __restrict__ W1t,
    const float* __restrict__ b1, const unsigned short* __restrict__ W2t,
    const float* __restrict__ b2, const float* __restrict__ scal,
    float* __restrict__ Lg, int N, int ntiles) {
    __shared__ unsigned short sW1[C_DIM][WPAD];   // 34.0 KB  [n][k]
    __shared__ unsigned short sW2[K_DIM][WPAD];   //  8.5 KB  [n][k]
    __shared__ unsigned short sX[64][WPAD];       // 17.0 KB  [row][k] bf16
    __shared__ unsigned short sH[4][16][WPAD];    // 17.0 KB  per-wave h
    __shared__ float sB1[C_DIM];
    __shared__ float sB2[K_DIM];

    const int tid = threadIdx.x;
    // ---- stage W (once): 16B chunks, padded rows ----
    for (int i = tid; i < C_DIM * 16; i += 256) {          // 2048 x 8 bf16
        const int r = i >> 4, c8 = (i & 15) * 8;
        *(float4*)&sW1[r][c8] = *(const float4*)&W1t[r * C_DIM + c8];
    }
    for (int i = tid; i < K_DIM * 16; i += 256) {          // 512 x 8 bf16
        const int r = i >> 4, c8 = (i & 15) * 8;
        *(float4*)&sW2[r][c8] = *(const float4*)&W2t[r * C_DIM + c8];
    }
    if (tid < C_DIM) sB1[tid] = b1[tid];
    if (tid < K_DIM) sB2[tid] = b2[tid];
    const float sc = *scal;

    const int wave = tid >> 6;
    const int lane = tid & 63;
    const int lr = lane & 15;     // frag row/col index
    const int kg = lane >> 4;     // k-group 0..3
    __syncthreads();

    for (int tile = blockIdx.x; tile < ntiles; tile += gridDim.x) {
        const int row0 = tile * 64;       // N % 64 == 0
        __syncthreads();  // previous tile consumed
        // ---- stage x tile as bf16 (convert during staging) ----
        for (int i = tid; i < 2048; i += 256) {
            const int r = i >> 5, c4 = (i & 31) * 4;
            const float4 v = *(const float4*)&x[(size_t)(row0 + r) * C_DIM + c4];
            us4 u;
            u.x = f2bf(v.x); u.y = f2bf(v.y); u.z = f2bf(v.z); u.w = f2bf(v.w);
            *(us4*)&sX[r][c4] = u;
        }
        __syncthreads();

        // ---- layer 1: h = relu(x@W1 + b1) ----
        short8 a[4];
#pragma unroll
        for (int kt = 0; kt < 4; ++kt)
            a[kt] = *(const short8*)&sX[wave * 16 + lr][kt * 32 + kg * 8];
#pragma unroll
        for (int ct = 0; ct < 8; ++ct) {
            const float bv = sB1[ct * 16 + lr];
            f32x4 acc = {bv, bv, bv, bv};
#pragma unroll
            for (int kt = 0; kt < 4; ++kt) {
                const short8 b = *(const short8*)&sW1[ct * 16 + lr][kt * 32 + kg * 8];
                acc = __builtin_amdgcn_mfma_f32_16x16x32_bf16(a[kt], b, acc, 0, 0, 0);
            }
#pragma unroll
            for (int r = 0; r < 4; ++r)
                sH[wave][kg * 4 + r][ct * 16 + lr] = f2bf(fmaxf(acc[r], 0.f));
        }
        __syncthreads();  // conservative (sH is wave-private)

        // ---- layer 2: L = (h@W2 + b2)*sc ----
        short8 a2[4];
#pragma unroll
        for (int kt = 0; kt < 4; ++kt)
            a2[kt] = *(const short8*)&sH[wave][lr][kt * 32 + kg * 8];
#pragma unroll
        for (int ct = 0; ct < 2; ++ct) {
            const float bv = sB2[ct * 16 + lr];
            f32x4 acc = {bv, bv, bv, bv};
#pragma unroll
            for (int kt = 0; kt < 4; ++kt) {
                const short8 b = *(const short8*)&sW2[ct * 16 + lr][kt * 32 + kg * 8];
                acc = __builtin_amdgcn_mfma_f32_16x16x32_bf16(a2[kt], b, acc, 0, 0, 0);
            }
#pragma unroll
            for (int r = 0; r < 4; ++r) {
                const int g = row0 + wave * 16 + kg * 4 + r;
                Lg[(size_t)g * K_DIM + ct * 16 + lr] = acc[r] * sc;
            }
        }
    }
}

// ---------------------------------------------------------------------------
// persistent Sinkhorn: all 20 iterations, L held in registers.
// 196 blocks x 1024 thr (1 row/thread), <=128 VGPR -> 1 block/CU, all resident.
// Per iter: row softmax -> fold-exchange column reduce (round-5 validated) ->
// block reduce -> sharded device atomics -> fresh-counter global barrier ->
// every block recomputes v update. After t=20: s written in-place to Lg.
// ---------------------------------------------------------------------------
__device__ __forceinline__ int bitrev5(int l) {
    return ((l & 1) << 4) | ((l & 2) << 2) | (l & 4) | ((l & 8) >> 2) |
           ((l & 16) >> 4);
}

#define FOLD_STAGE(M, HALF)                                   \
    {                                                         \
        const bool hi = (lane & (M)) != 0;                    \
        _Pragma("unroll")                                     \
        for (int j = 0; j < (HALF); ++j) {                    \
            const float give = hi ? p[j] : p[j + (HALF)];     \
            const float keep = hi ? p[j + (HALF)] : p[j];     \
            p[j] = keep + __shfl_xor(give, (M));              \
        }                                                     \
    }

__global__ __launch_bounds__(1024, 4) void sinkhorn_kernel(
    float* __restrict__ Lg, float* __restrict__ shards, int* __restrict__ arrive,
    int N, int nblocks) {
    __shared__ float sv[K_DIM];
    __shared__ float swsum[16][K_DIM];
    __shared__ float sdl[K_DIM];
    const int tid = threadIdx.x;
    const int wave = tid >> 6;
    const int lane = tid & 63;
    const size_t n = (size_t)blockIdx.x * 1024 + tid;
    const bool valid = n < (size_t)N;
    const int myshard = blockIdx.x & (NSHARD - 1);
    const float log_tgt = __logf((float)N / (float)K_DIM);

    if (tid < K_DIM) sv[tid] = 0.f;

    float L[K_DIM];
    if (valid) {
        const float4* Lr = (const float4*)(Lg + n * K_DIM);
#pragma unroll
        for (int j = 0; j < 8; ++j) {
            const float4 v = Lr[j];
            L[4 * j] = v.x; L[4 * j + 1] = v.y; L[4 * j + 2] = v.z; L[4 * j + 3] = v.w;
        }
    } else {
#pragma unroll
        for (int j = 0; j < K_DIM; ++j) L[j] = 0.f;
    }
    __syncthreads();

    float m0 = 0.f, inv = 0.f;
    for (int t = 1; t <= N_ITERS; ++t) {
        float p[K_DIM];
        if (valid) {
#pragma unroll
            for (int j = 0; j < K_DIM; ++j) p[j] = L[j] - sv[j];
            m0 = p[0];
#pragma unroll
            for (int j = 1; j < K_DIM; ++j) m0 = fmaxf(m0, p[j]);
            float sum = 0.f;
#pragma unroll
            for (int j = 0; j < K_DIM; ++j) {
                p[j] = __expf(p[j] - m0);
                sum += p[j];
            }
            inv = 1.f / sum;
#pragma unroll
            for (int j = 0; j < K_DIM; ++j) p[j] *= inv;
        } else {
#pragma unroll
            for (int j = 0; j < K_DIM; ++j) p[j] = 0.f;
        }

        FOLD_STAGE(1, 16)
        FOLD_STAGE(2, 8)
        FOLD_STAGE(4, 4)
        FOLD_STAGE(8, 2)
        FOLD_STAGE(16, 1)
        const float tot = p[0] + __shfl_xor(p[0], 32);
        if (lane < K_DIM) swsum[wave][bitrev5(lane)] = tot;
        __syncthreads();
        if (tid < K_DIM) {
            float s_ = 0.f;
#pragma unroll
            for (int w = 0; w < 16; ++w) s_ += swsum[w][tid];
            atomicAdd(&shards[((size_t)t * NSHARD + myshard) * K_DIM + tid], s_);
        }
        __syncthreads();   // all 32 atomics issued before arrival
        __threadfence();
        if (tid == 0) {
            __hip_atomic_fetch_add(arrive + t, 1, __ATOMIC_RELEASE,
                                   __HIP_MEMORY_SCOPE_AGENT);
            while (__hip_atomic_load(arrive + t, __ATOMIC_ACQUIRE,
                                     __HIP_MEMORY_SCOPE_AGENT) < nblocks)
                __builtin_amdgcn_s_sleep(2);
        }
        __syncthreads();

        if (tid < K_DIM) {
            float cs = 0.f;
#pragma unroll
            for (int sh = 0; sh < NSHARD; ++sh)
                cs += __hip_atomic_load(
                    &shards[((size_t)t * NSHARD + sh) * K_DIM + tid],
                    __ATOMIC_RELAXED, __HIP_MEMORY_SCOPE_AGENT);
            if (t < N_ITERS)
                sv[tid] += __logf(cs) - log_tgt;
            else
                sdl[tid] = ((float)N / (float)K_DIM) / cs;   // sd; sv stays = v19
        }
        __syncthreads();
    }

    // s = exp(L - v19 - m0) * inv * sd  (m0/inv from iteration 20)
    if (valid) {
        float4* Sr = (float4*)(Lg + n * K_DIM);
#pragma unroll
        for (int j = 0; j < 8; ++j) {
            float4 o;
            o.x = __expf(L[4 * j + 0] - sv[4 * j + 0] - m0) * inv * sdl[4 * j + 0];
            o.y = __expf(L[4 * j + 1] - sv[4 * j + 1] - m0) * inv * sdl[4 * j + 1];
            o.z = __expf(L[4 * j + 2] - sv[4 * j + 2] - m0) * inv * sdl[4 * j + 2];
            o.w = __expf(L[4 * j + 3] - sv[4 * j + 3] - m0) * inv * sdl[4 * j + 3];
            Sr[j] = o;
        }
    }
}

// ---------------------------------------------------------------------------
// final pooling: out[b,k,c] += s[n,k]*x[n,c], s precomputed in Sg (= Lg).
// batch sorted -> contiguous segments; register accumulators, flush on change.
// ---------------------------------------------------------------------------
#define PCHUNK 96
#define PCH_PER_BLOCK 4

__global__ __launch_bounds__(256) void pool_kernel(
    const float* __restrict__ x, const int* __restrict__ batch,
    const float* __restrict__ Sg, float* __restrict__ out, int N) {
    __shared__ float sx[PCHUNK][C_DIM];   // 48 KB
    __shared__ float ss[PCHUNK][K_DIM];   // 12 KB
    __shared__ int sb[PCHUNK];

    const int tid = threadIdx.x;
    const int k0 = (tid >> 5) * 4;
    const int c0 = (tid & 31) * 4;
    float acc[4][4];
#pragma unroll
    for (int i = 0; i < 4; ++i)
#pragma unroll
        for (int j = 0; j < 4; ++j) acc[i][j] = 0.f;

    int cur_b = -1;
    const int base0 = blockIdx.x * (PCHUNK * PCH_PER_BLOCK);

    for (int cc = 0; cc < PCH_PER_BLOCK; ++cc) {
        const int base = base0 + cc * PCHUNK;
        if (base >= N) break;  // block-uniform
        const int rows = min(PCHUNK, N - base);
        __syncthreads();
        {
            const float4* src = (const float4*)(x + (size_t)base * C_DIM);
            for (int i = tid; i < rows * (C_DIM / 4); i += 256)
                ((float4*)&sx[0][0])[i] = src[i];
            const float4* ssrc = (const float4*)(Sg + (size_t)base * K_DIM);
            for (int i = tid; i < rows * (K_DIM / 4); i += 256)
                ((float4*)&ss[0][0])[i] = ssrc[i];
        }
        if (tid < rows) sb[tid] = batch[base + tid];
        __syncthreads();

        for (int r = 0; r < rows; ++r) {
            const int b = sb[r];  // uniform across block
            if (b != cur_b) {
                if (cur_b >= 0) {
                    float* ob = out + ((size_t)cur_b * K_DIM + k0) * C_DIM + c0;
#pragma unroll
                    for (int i = 0; i < 4; ++i)
#pragma unroll
                        for (int j = 0; j < 4; ++j) {
                            atomicAdd(&ob[i * C_DIM + j], acc[i][j]);
                            acc[i][j] = 0.f;
                        }
                }
                cur_b = b;
            }
            const float4 sv = *(const float4*)&ss[r][k0];
            const float4 xv = *(const float4*)&sx[r][c0];
            const float sA[4] = {sv.x, sv.y, sv.z, sv.w};
            const float xA[4] = {xv.x, xv.y, xv.z, xv.w};
#pragma unroll
            for (int i = 0; i < 4; ++i)
#pragma unroll
                for (int j = 0; j < 4; ++j)
                    acc[i][j] = fmaf(sA[i], xA[j], acc[i][j]);
        }
    }
    if (cur_b >= 0) {
        float* ob = out + ((size_t)cur_b * K_DIM + k0) * C_DIM + c0;
#pragma unroll
        for (int i = 0; i < 4; ++i)
#pragma unroll
            for (int j = 0; j < 4; ++j) atomicAdd(&ob[i * C_DIM + j], acc[i][j]);
    }
}

// ---------------------------------------------------------------------------
extern "C" void kernel_launch(void* const* d_in, const int* in_sizes, int n_in,
                              void* d_out, int out_size, void* d_ws, size_t ws_size,
                              hipStream_t stream) {
    const float* x = (const float*)d_in[0];
    const int* batch = (const int*)d_in[1];
    const float* W1 = (const float*)d_in[2];
    const float* b1 = (const float*)d_in[3];
    const float* W2 = (const float*)d_in[4];
    const float* b2 = (const float*)d_in[5];
    const float* scal = (const float*)d_in[6];
    float* out = (float*)d_out;

    const int N = in_sizes[1];  // 200000

    // ws layout (floats): L/S [N*32] | shards [21*16*32] | arrive [64 ints]
    //                     | W1t [16384 bf16] | W2t [4096 bf16]
    float* Lg = (float*)d_ws;
    float* shards = Lg + (size_t)N * K_DIM;
    const int n_shard_f = (N_ITERS + 1) * NSHARD * K_DIM;   // 10752
    int* arrive = (int*)(shards + n_shard_f);
    unsigned short* W1t = (unsigned short*)(arrive + 64);
    unsigned short* W2t = W1t + C_DIM * C_DIM;

    init_kernel<<<64, 256, 0, stream>>>(out, out_size, shards, n_shard_f + 64,
                                        W1, W2, W1t, W2t);

    const int ntiles = N / 64;  // 3125
    mlp_kernel<<<640, 256, 0, stream>>>(x, W1t, b1, W2t, b2, scal, Lg, N, ntiles);

    const int sblocks = (N + 1023) / 1024;  // 196 <= 256 CUs -> all resident
    sinkhorn_kernel<<<sblocks, 1024, 0, stream>>>(Lg, shards, arrive, N, sblocks);

    const int pblocks = (N + PCHUNK * PCH_PER_BLOCK - 1) / (PCHUNK * PCH_PER_BLOCK);
    pool_kernel<<<pblocks, 256, 0, stream>>>(x, batch, Lg, out, N);
}

// Round 7
// 486.194 us; speedup vs baseline: 2.9249x; 2.9249x over previous
//
#include <hip/hip_runtime.h>
#include <hip/hip_bf16.h>

// Problem constants: N=200000, C=128, K=32, B=16, 20 Sinkhorn iters.
#define C_DIM 128
#define K_DIM 32
#define N_ITERS 20
#define NSHARD 16
#define WPAD 136   // bf16 row pad: 136*2B = 272B = 68 words -> bank step 4/row (2-way = free)

typedef __attribute__((ext_vector_type(8))) short short8;      // 8 bf16 (4 VGPR) MFMA A/B frag
typedef __attribute__((ext_vector_type(4))) float f32x4;       // MFMA C/D frag
typedef __attribute__((ext_vector_type(4))) unsigned short us4;

__device__ __forceinline__ unsigned short f2bf(float f) {
    __hip_bfloat16 h = __float2bfloat16(f);   // round-to-nearest
    return *reinterpret_cast<unsigned short*>(&h);
}

// ---------------------------------------------------------------------------
// init: zero out / shards / barrier counters; transpose+convert W1,W2 to bf16
// ---------------------------------------------------------------------------
__global__ void init_kernel(float* __restrict__ out, int n_out,
                            float* __restrict__ zreg, int n_z,
                            const float* __restrict__ W1, const float* __restrict__ W2,
                            unsigned short* __restrict__ W1t,
                            unsigned short* __restrict__ W2t) {
    int i = blockIdx.x * blockDim.x + threadIdx.x;
    int stride = gridDim.x * blockDim.x;
    for (int j = i; j < n_out; j += stride) out[j] = 0.f;
    for (int j = i; j < n_z; j += stride) zreg[j] = 0.f;
    for (int j = i; j < C_DIM * C_DIM; j += stride) {   // W1t[n][k] = W1[k][n]
        int n = j >> 7, k = j & 127;
        W1t[j] = f2bf(W1[k * C_DIM + n]);
    }
    for (int j = i; j < C_DIM * K_DIM; j += stride) {   // W2t[n][k] = W2[k][n]
        int n = j >> 7, k = j & 127;
        W2t[j] = f2bf(W2[k * K_DIM + n]);
    }
}

// ---------------------------------------------------------------------------
// MFMA MLP: L = (relu(x@W1 + b1) @ W2 + b2) * sc, bf16 inputs / fp32 accum.
// (byte-identical to round 6 — correctness validated, timing to be read)
// ---------------------------------------------------------------------------
__global__ __launch_bounds__(256, 4) void mlp_kernel(
    const float* __restrict__ x, const unsigned short* __restrict__ W1t,
    const float* __restrict__ b1, const unsigned short* __restrict__ W2t,
    const float* __restrict__ b2, const float* __restrict__ scal,
    float* __restrict__ Lg, int N, int ntiles) {
    __shared__ unsigned short sW1[C_DIM][WPAD];   // 34.0 KB  [n][k]
    __shared__ unsigned short sW2[K_DIM][WPAD];   //  8.5 KB  [n][k]
    __shared__ unsigned short sX[64][WPAD];       // 17.0 KB  [row][k] bf16
    __shared__ unsigned short sH[4][16][WPAD];    // 17.0 KB  per-wave h
    __shared__ float sB1[C_DIM];
    __shared__ float sB2[K_DIM];

    const int tid = threadIdx.x;
    for (int i = tid; i < C_DIM * 16; i += 256) {
        const int r = i >> 4, c8 = (i & 15) * 8;
        *(float4*)&sW1[r][c8] = *(const float4*)&W1t[r * C_DIM + c8];
    }
    for (int i = tid; i < K_DIM * 16; i += 256) {
        const int r = i >> 4, c8 = (i & 15) * 8;
        *(float4*)&sW2[r][c8] = *(const float4*)&W2t[r * C_DIM + c8];
    }
    if (tid < C_DIM) sB1[tid] = b1[tid];
    if (tid < K_DIM) sB2[tid] = b2[tid];
    const float sc = *scal;

    const int wave = tid >> 6;
    const int lane = tid & 63;
    const int lr = lane & 15;
    const int kg = lane >> 4;
    __syncthreads();

    for (int tile = blockIdx.x; tile < ntiles; tile += gridDim.x) {
        const int row0 = tile * 64;       // N % 64 == 0
        __syncthreads();
        for (int i = tid; i < 2048; i += 256) {
            const int r = i >> 5, c4 = (i & 31) * 4;
            const float4 v = *(const float4*)&x[(size_t)(row0 + r) * C_DIM + c4];
            us4 u;
            u.x = f2bf(v.x); u.y = f2bf(v.y); u.z = f2bf(v.z); u.w = f2bf(v.w);
            *(us4*)&sX[r][c4] = u;
        }
        __syncthreads();

        short8 a[4];
#pragma unroll
        for (int kt = 0; kt < 4; ++kt)
            a[kt] = *(const short8*)&sX[wave * 16 + lr][kt * 32 + kg * 8];
#pragma unroll
        for (int ct = 0; ct < 8; ++ct) {
            const float bv = sB1[ct * 16 + lr];
            f32x4 acc = {bv, bv, bv, bv};
#pragma unroll
            for (int kt = 0; kt < 4; ++kt) {
                const short8 b = *(const short8*)&sW1[ct * 16 + lr][kt * 32 + kg * 8];
                acc = __builtin_amdgcn_mfma_f32_16x16x32_bf16(a[kt], b, acc, 0, 0, 0);
            }
#pragma unroll
            for (int r = 0; r < 4; ++r)
                sH[wave][kg * 4 + r][ct * 16 + lr] = f2bf(fmaxf(acc[r], 0.f));
        }
        __syncthreads();

        short8 a2[4];
#pragma unroll
        for (int kt = 0; kt < 4; ++kt)
            a2[kt] = *(const short8*)&sH[wave][lr][kt * 32 + kg * 8];
#pragma unroll
        for (int ct = 0; ct < 2; ++ct) {
            const float bv = sB2[ct * 16 + lr];
            f32x4 acc = {bv, bv, bv, bv};
#pragma unroll
            for (int kt = 0; kt < 4; ++kt) {
                const short8 b = *(const short8*)&sW2[ct * 16 + lr][kt * 32 + kg * 8];
                acc = __builtin_amdgcn_mfma_f32_16x16x32_bf16(a2[kt], b, acc, 0, 0, 0);
            }
#pragma unroll
            for (int r = 0; r < 4; ++r) {
                const int g = row0 + wave * 16 + kg * 4 + r;
                Lg[(size_t)g * K_DIM + ct * 16 + lr] = acc[r] * sc;
            }
        }
    }
}

// ---------------------------------------------------------------------------
// persistent Sinkhorn, pure-atomic global barrier (NO threadfence, NO
// acquire/release cache flushes — all cross-block data moves through
// device-scope atomics at the coherence point; completion enforced by
// s_waitcnt vmcnt(0) before arrival).
// ---------------------------------------------------------------------------
__device__ __forceinline__ int bitrev5(int l) {
    return ((l & 1) << 4) | ((l & 2) << 2) | (l & 4) | ((l & 8) >> 2) |
           ((l & 16) >> 4);
}

#define FOLD_STAGE(M, HALF)                                   \
    {                                                         \
        const bool hi = (lane & (M)) != 0;                    \
        _Pragma("unroll")                                     \
        for (int j = 0; j < (HALF); ++j) {                    \
            const float give = hi ? p[j] : p[j + (HALF)];     \
            const float keep = hi ? p[j + (HALF)] : p[j];     \
            p[j] = keep + __shfl_xor(give, (M));              \
        }                                                     \
    }

__global__ __launch_bounds__(1024, 4) void sinkhorn_kernel(
    float* __restrict__ Lg, float* __restrict__ shards, int* __restrict__ arrive,
    int N, int nblocks) {
    __shared__ float sv[K_DIM];
    __shared__ float swsum[16][K_DIM];
    __shared__ float sdl[K_DIM];
    const int tid = threadIdx.x;
    const int wave = tid >> 6;
    const int lane = tid & 63;
    const size_t n = (size_t)blockIdx.x * 1024 + tid;
    const bool valid = n < (size_t)N;
    const int myshard = blockIdx.x & (NSHARD - 1);
    const float log_tgt = __logf((float)N / (float)K_DIM);

    if (tid < K_DIM) sv[tid] = 0.f;

    float L[K_DIM];
    if (valid) {
        const float4* Lr = (const float4*)(Lg + n * K_DIM);
#pragma unroll
        for (int j = 0; j < 8; ++j) {
            const float4 v = Lr[j];
            L[4 * j] = v.x; L[4 * j + 1] = v.y; L[4 * j + 2] = v.z; L[4 * j + 3] = v.w;
        }
    } else {
#pragma unroll
        for (int j = 0; j < K_DIM; ++j) L[j] = 0.f;
    }
    __syncthreads();

    float m0 = 0.f, inv = 0.f;
    for (int t = 1; t <= N_ITERS; ++t) {
        float p[K_DIM];
        if (valid) {
#pragma unroll
            for (int j = 0; j < K_DIM; ++j) p[j] = L[j] - sv[j];
            m0 = p[0];
#pragma unroll
            for (int j = 1; j < K_DIM; ++j) m0 = fmaxf(m0, p[j]);
            float sum = 0.f;
#pragma unroll
            for (int j = 0; j < K_DIM; ++j) {
                p[j] = __expf(p[j] - m0);
                sum += p[j];
            }
            inv = 1.f / sum;
#pragma unroll
            for (int j = 0; j < K_DIM; ++j) p[j] *= inv;
        } else {
#pragma unroll
            for (int j = 0; j < K_DIM; ++j) p[j] = 0.f;
        }

        FOLD_STAGE(1, 16)
        FOLD_STAGE(2, 8)
        FOLD_STAGE(4, 4)
        FOLD_STAGE(8, 2)
        FOLD_STAGE(16, 1)
        const float tot = p[0] + __shfl_xor(p[0], 32);
        if (lane < K_DIM) swsum[wave][bitrev5(lane)] = tot;
        __syncthreads();
        if (tid < K_DIM) {
            float s_ = 0.f;
#pragma unroll
            for (int w = 0; w < 16; ++w) s_ += swsum[w][tid];
            atomicAdd(&shards[((size_t)t * NSHARD + myshard) * K_DIM + tid], s_);
        }
        // wait for MY atomics to complete at the coherence point (they count
        // in vmcnt); no cache fence needed — atomics bypass to coherence pt.
        asm volatile("s_waitcnt vmcnt(0)" ::: "memory");
        __syncthreads();
        if (tid == 0) {
            __hip_atomic_fetch_add(arrive + t, 1, __ATOMIC_RELAXED,
                                   __HIP_MEMORY_SCOPE_AGENT);
            while (__hip_atomic_load(arrive + t, __ATOMIC_RELAXED,
                                     __HIP_MEMORY_SCOPE_AGENT) < nblocks)
                __builtin_amdgcn_s_sleep(16);
        }
        __syncthreads();

        if (tid < K_DIM) {
            float cs = 0.f;
#pragma unroll
            for (int sh = 0; sh < NSHARD; ++sh)
                cs += __hip_atomic_load(
                    &shards[((size_t)t * NSHARD + sh) * K_DIM + tid],
                    __ATOMIC_RELAXED, __HIP_MEMORY_SCOPE_AGENT);
            if (t < N_ITERS)
                sv[tid] += __logf(cs) - log_tgt;
            else
                sdl[tid] = ((float)N / (float)K_DIM) / cs;   // sd; sv stays = v19
        }
        __syncthreads();
    }

    // s = exp(L - v19 - m0) * inv * sd  (m0/inv from iteration 20)
    if (valid) {
        float4* Sr = (float4*)(Lg + n * K_DIM);
#pragma unroll
        for (int j = 0; j < 8; ++j) {
            float4 o;
            o.x = __expf(L[4 * j + 0] - sv[4 * j + 0] - m0) * inv * sdl[4 * j + 0];
            o.y = __expf(L[4 * j + 1] - sv[4 * j + 1] - m0) * inv * sdl[4 * j + 1];
            o.z = __expf(L[4 * j + 2] - sv[4 * j + 2] - m0) * inv * sdl[4 * j + 2];
            o.w = __expf(L[4 * j + 3] - sv[4 * j + 3] - m0) * inv * sdl[4 * j + 3];
            Sr[j] = o;
        }
    }
}

// ---------------------------------------------------------------------------
// final pooling: out[b,k,c] += s[n,k]*x[n,c], s precomputed in Sg (= Lg).
// (byte-identical to round 6)
// ---------------------------------------------------------------------------
#define PCHUNK 96
#define PCH_PER_BLOCK 4

__global__ __launch_bounds__(256) void pool_kernel(
    const float* __restrict__ x, const int* __restrict__ batch,
    const float* __restrict__ Sg, float* __restrict__ out, int N) {
    __shared__ float sx[PCHUNK][C_DIM];   // 48 KB
    __shared__ float ss[PCHUNK][K_DIM];   // 12 KB
    __shared__ int sb[PCHUNK];

    const int tid = threadIdx.x;
    const int k0 = (tid >> 5) * 4;
    const int c0 = (tid & 31) * 4;
    float acc[4][4];
#pragma unroll
    for (int i = 0; i < 4; ++i)
#pragma unroll
        for (int j = 0; j < 4; ++j) acc[i][j] = 0.f;

    int cur_b = -1;
    const int base0 = blockIdx.x * (PCHUNK * PCH_PER_BLOCK);

    for (int cc = 0; cc < PCH_PER_BLOCK; ++cc) {
        const int base = base0 + cc * PCHUNK;
        if (base >= N) break;  // block-uniform
        const int rows = min(PCHUNK, N - base);
        __syncthreads();
        {
            const float4* src = (const float4*)(x + (size_t)base * C_DIM);
            for (int i = tid; i < rows * (C_DIM / 4); i += 256)
                ((float4*)&sx[0][0])[i] = src[i];
            const float4* ssrc = (const float4*)(Sg + (size_t)base * K_DIM);
            for (int i = tid; i < rows * (K_DIM / 4); i += 256)
                ((float4*)&ss[0][0])[i] = ssrc[i];
        }
        if (tid < rows) sb[tid] = batch[base + tid];
        __syncthreads();

        for (int r = 0; r < rows; ++r) {
            const int b = sb[r];  // uniform across block
            if (b != cur_b) {
                if (cur_b >= 0) {
                    float* ob = out + ((size_t)cur_b * K_DIM + k0) * C_DIM + c0;
#pragma unroll
                    for (int i = 0; i < 4; ++i)
#pragma unroll
                        for (int j = 0; j < 4; ++j) {
                            atomicAdd(&ob[i * C_DIM + j], acc[i][j]);
                            acc[i][j] = 0.f;
                        }
                }
                cur_b = b;
            }
            const float4 sv = *(const float4*)&ss[r][k0];
            const float4 xv = *(const float4*)&sx[r][c0];
            const float sA[4] = {sv.x, sv.y, sv.z, sv.w};
            const float xA[4] = {xv.x, xv.y, xv.z, xv.w};
#pragma unroll
            for (int i = 0; i < 4; ++i)
#pragma unroll
                for (int j = 0; j < 4; ++j)
                    acc[i][j] = fmaf(sA[i], xA[j], acc[i][j]);
        }
    }
    if (cur_b >= 0) {
        float* ob = out + ((size_t)cur_b * K_DIM + k0) * C_DIM + c0;
#pragma unroll
        for (int i = 0; i < 4; ++i)
#pragma unroll
            for (int j = 0; j < 4; ++j) atomicAdd(&ob[i * C_DIM + j], acc[i][j]);
    }
}

// ---------------------------------------------------------------------------
extern "C" void kernel_launch(void* const* d_in, const int* in_sizes, int n_in,
                              void* d_out, int out_size, void* d_ws, size_t ws_size,
                              hipStream_t stream) {
    const float* x = (const float*)d_in[0];
    const int* batch = (const int*)d_in[1];
    const float* W1 = (const float*)d_in[2];
    const float* b1 = (const float*)d_in[3];
    const float* W2 = (const float*)d_in[4];
    const float* b2 = (const float*)d_in[5];
    const float* scal = (const float*)d_in[6];
    float* out = (float*)d_out;

    const int N = in_sizes[1];  // 200000

    // ws layout (floats): L/S [N*32] | shards [21*16*32] | arrive [64 ints]
    //                     | W1t [16384 bf16] | W2t [4096 bf16]
    float* Lg = (float*)d_ws;
    float* shards = Lg + (size_t)N * K_DIM;
    const int n_shard_f = (N_ITERS + 1) * NSHARD * K_DIM;   // 10752
    int* arrive = (int*)(shards + n_shard_f);
    unsigned short* W1t = (unsigned short*)(arrive + 64);
    unsigned short* W2t = W1t + C_DIM * C_DIM;

    init_kernel<<<64, 256, 0, stream>>>(out, out_size, shards, n_shard_f + 64,
                                        W1, W2, W1t, W2t);

    const int ntiles = N / 64;  // 3125
    mlp_kernel<<<640, 256, 0, stream>>>(x, W1t, b1, W2t, b2, scal, Lg, N, ntiles);

    const int sblocks = (N + 1023) / 1024;  // 196 <= 256 CUs -> all resident
    sinkhorn_kernel<<<sblocks, 1024, 0, stream>>>(Lg, shards, arrive, N, sblocks);

    const int pblocks = (N + PCHUNK * PCH_PER_BLOCK - 1) / (PCHUNK * PCH_PER_BLOCK);
    pool_kernel<<<pblocks, 256, 0, stream>>>(x, batch, Lg, out, N);
}